// Round 17
// baseline (534.552 us; speedup 1.0000x reference)
//
#include <hip/hip_runtime.h>
#include <math.h>

// ---------------------------------------------------------------------------
// 3-layer GCN forward.  (R13 structure + degree-sorted agg processing order)
//   1. deg count — XCD-partitioned by dst range
//   2. two-level exclusive scan -> rowptr + cursor (+ fused dinv)
//   3. CSR fill — XCD-partitioned by dst range
//   4. counting-sort nodes by degree -> order[] (aliases dead cursor buffer);
//      agg processes nodes via order[] so each wave's 16 nodes have ~equal
//      degree (no max-of-16 divergence on the serial gather chain).
//   5. all layers: GEMM (W slab in 32KB LDS, R=4) writes CHUNK-MAJOR
//      [OUT/16][N][16]; XCD-local chunked aggregate (4 lanes x float4/node,
//      8-deep predicated unroll) writes row-major.
// ---------------------------------------------------------------------------

__global__ __launch_bounds__(256) void count_part_kernel(const int* __restrict__ col,
                                                         int* __restrict__ deg, int E, int n) {
    const int part = blockIdx.x & 7;
    const int nb = gridDim.x >> 3;
    const int chunk = blockIdx.x >> 3;
    const int lo = (int)(((long long)part * n) >> 3);
    const int hi = (int)(((long long)(part + 1) * n) >> 3);
    for (int e = chunk * 256 + threadIdx.x; e < E; e += nb * 256) {
        const int c = col[e];
        if (c >= lo && c < hi) atomicAdd(&deg[c], 1);
    }
}

__global__ __launch_bounds__(256) void scan1_kernel(const int* __restrict__ deg,
                                                    int* __restrict__ local,
                                                    int* __restrict__ blocksums, int n) {
    __shared__ int wsum[4];
    const int t = threadIdx.x;
    const int lane = t & 63;
    const int wv = t >> 6;
    const int base = blockIdx.x * 1024 + t * 4;
    int a0 = (base + 0 < n) ? deg[base + 0] : 0;
    int a1 = (base + 1 < n) ? deg[base + 1] : 0;
    int a2 = (base + 2 < n) ? deg[base + 2] : 0;
    int a3 = (base + 3 < n) ? deg[base + 3] : 0;
    const int tot = a0 + a1 + a2 + a3;
    int incl = tot;
#pragma unroll
    for (int off = 1; off < 64; off <<= 1) {
        int u = __shfl_up(incl, off);
        if (lane >= off) incl += u;
    }
    if (lane == 63) wsum[wv] = incl;
    __syncthreads();
    int woff = 0;
#pragma unroll
    for (int w = 0; w < 4; ++w) woff += (w < wv) ? wsum[w] : 0;
    const int excl = woff + incl - tot;
    if (base + 0 < n) local[base + 0] = excl;
    if (base + 1 < n) local[base + 1] = excl + a0;
    if (base + 2 < n) local[base + 2] = excl + a0 + a1;
    if (base + 3 < n) local[base + 3] = excl + a0 + a1 + a2;
    if (t == 255) blocksums[blockIdx.x] = woff + incl;
}

__global__ void scan2_kernel(const int* __restrict__ blocksums, int* __restrict__ blockoff,
                             int* __restrict__ rowptr, int nb, int n) {
    const int lane = threadIdx.x;  // 64 threads
    int v = (lane < nb) ? blocksums[lane] : 0;
    int incl = v;
#pragma unroll
    for (int off = 1; off < 64; off <<= 1) {
        int u = __shfl_up(incl, off);
        if (lane >= off) incl += u;
    }
    if (lane < nb) blockoff[lane] = incl - v;
    if (lane == 63) rowptr[n] = incl;
}

__global__ void scan3_kernel(const int* __restrict__ local, const int* __restrict__ blockoff,
                             const int* __restrict__ deg, int* __restrict__ rowptr,
                             int* __restrict__ cursor, float* __restrict__ dinv, int n) {
    int i = blockIdx.x * blockDim.x + threadIdx.x;
    if (i < n) {
        const int v = local[i] + blockoff[i >> 10];
        rowptr[i] = v;
        cursor[i] = v;
        dinv[i] = rsqrtf((float)deg[i] + 1.0f);
    }
}

__global__ __launch_bounds__(256) void fill_part_kernel(const int* __restrict__ row,
                                                        const int* __restrict__ col,
                                                        int* __restrict__ cursor,
                                                        int* __restrict__ csr, int E, int n) {
    const int part = blockIdx.x & 7;
    const int nb = gridDim.x >> 3;
    const int chunk = blockIdx.x >> 3;
    const int lo = (int)(((long long)part * n) >> 3);
    const int hi = (int)(((long long)(part + 1) * n) >> 3);
    for (int e = chunk * 256 + threadIdx.x; e < E; e += nb * 256) {
        const int c = col[e];
        if (c >= lo && c < hi) {
            const int r = row[e];
            if ((unsigned)r < (unsigned)n) {
                const int pos = atomicAdd(&cursor[c], 1);
                csr[pos] = r;
            }
        }
    }
}

// Degree-bucket counting sort: bc[min(deg,63)]++
__global__ void bucket_count_kernel(const int* __restrict__ deg, int* __restrict__ bc, int n) {
    int i = blockIdx.x * blockDim.x + threadIdx.x;
    if (i < n) {
        int b = deg[i]; b = (b < 63) ? b : 63;
        atomicAdd(&bc[b], 1);
    }
}

// One wave: exclusive-scan the 64 bucket counts -> bucket cursors.
__global__ void bucket_scan_kernel(const int* __restrict__ bc, int* __restrict__ bcur) {
    const int lane = threadIdx.x;  // 64 threads
    int v = bc[lane];
    int incl = v;
#pragma unroll
    for (int off = 1; off < 64; off <<= 1) {
        int u = __shfl_up(incl, off);
        if (lane >= off) incl += u;
    }
    bcur[lane] = incl - v;
}

__global__ void bucket_scatter_kernel(const int* __restrict__ deg, int* __restrict__ bcur,
                                      int* __restrict__ order, int n) {
    int i = blockIdx.x * blockDim.x + threadIdx.x;
    if (i < n) {
        int b = deg[i]; b = (b < 63) ? b : 63;
        const int pos = atomicAdd(&bcur[b], 1);
        order[pos] = i;
    }
}

// h[:, c0:c0+COLS] = X @ W[:, c0:c0+COLS], row r scaled by dinv[r].
// W column-slab staged in LDS (COLS=64 -> 32KB -> 5 blocks/CU). R=4 rows
// register-blocked per thread: 16 LDS floats feed 64 FMAs.
// CM: output chunk-major [OUT/16][n][16]; else row-major [n][OUT].
template <int OUT, int COLS, bool CM>
__global__ __launch_bounds__(256) void gemm_kernel(const float* __restrict__ X,
                                                   const float* __restrict__ W,
                                                   const float* __restrict__ dinv,
                                                   float* __restrict__ out, int n) {
    constexpr int NSLAB = OUT / COLS;
    constexpr int CQ  = COLS / 4;
    constexpr int RG  = 256 / CQ;
    constexpr int R   = 4;
    constexpr int RPI = RG * R;
    __shared__ float Wl[128 * COLS];

    const int t = threadIdx.x;
    const int c0 = (int)(blockIdx.x % NSLAB) * COLS;
    const int rowblk = blockIdx.x / NSLAB;

    for (int i = t; i < 128 * CQ; i += 256) {
        const int k  = i / CQ;
        const int cc = i % CQ;
        ((float4*)Wl)[i] = *(const float4*)&W[(size_t)k * OUT + c0 + cc * 4];
    }
    __syncthreads();

    const int cq = t % CQ;
    const int rg = t / CQ;
    const float4* X4 = (const float4*)X;
    const int gcol = c0 + cq * 4;                 // global output column
    const size_t cm_base = (size_t)(gcol >> 4) * n * 16 + (gcol & 15);

    const int r0 = rowblk * RPI + rg * R;
    float4 acc[R];
#pragma unroll
    for (int r = 0; r < R; ++r) acc[r] = make_float4(0.f, 0.f, 0.f, 0.f);

    if (r0 + R <= n) {
#pragma unroll 4
        for (int k4 = 0; k4 < 32; ++k4) {
            const float* wp = &Wl[k4 * 4 * COLS + cq * 4];
            float4 w0 = *(const float4*)(wp);
            float4 w1 = *(const float4*)(wp + COLS);
            float4 w2 = *(const float4*)(wp + 2 * COLS);
            float4 w3 = *(const float4*)(wp + 3 * COLS);
#pragma unroll
            for (int r = 0; r < R; ++r) {
                float4 xv = X4[(size_t)(r0 + r) * 32 + k4];
                acc[r].x = fmaf(xv.x, w0.x, acc[r].x);
                acc[r].x = fmaf(xv.y, w1.x, acc[r].x);
                acc[r].x = fmaf(xv.z, w2.x, acc[r].x);
                acc[r].x = fmaf(xv.w, w3.x, acc[r].x);
                acc[r].y = fmaf(xv.x, w0.y, acc[r].y);
                acc[r].y = fmaf(xv.y, w1.y, acc[r].y);
                acc[r].y = fmaf(xv.z, w2.y, acc[r].y);
                acc[r].y = fmaf(xv.w, w3.y, acc[r].y);
                acc[r].z = fmaf(xv.x, w0.z, acc[r].z);
                acc[r].z = fmaf(xv.y, w1.z, acc[r].z);
                acc[r].z = fmaf(xv.z, w2.z, acc[r].z);
                acc[r].z = fmaf(xv.w, w3.z, acc[r].z);
                acc[r].w = fmaf(xv.x, w0.w, acc[r].w);
                acc[r].w = fmaf(xv.y, w1.w, acc[r].w);
                acc[r].w = fmaf(xv.z, w2.w, acc[r].w);
                acc[r].w = fmaf(xv.w, w3.w, acc[r].w);
            }
        }
#pragma unroll
        for (int r = 0; r < R; ++r) {
            const float s = dinv[r0 + r];
            acc[r].x *= s; acc[r].y *= s; acc[r].z *= s; acc[r].w *= s;
            float* dst = CM ? &out[cm_base + (size_t)(r0 + r) * 16]
                            : &out[(size_t)(r0 + r) * OUT + gcol];
            *(float4*)dst = acc[r];
        }
    } else if (r0 < n) {
        for (int r = 0; r < R; ++r) {
            const int row = r0 + r;
            if (row >= n) break;
            float4 a = make_float4(0.f, 0.f, 0.f, 0.f);
            for (int k4 = 0; k4 < 32; ++k4) {
                float4 xv = X4[(size_t)row * 32 + k4];
                const float* wp = &Wl[k4 * 4 * COLS + cq * 4];
                float4 w0 = *(const float4*)(wp);
                float4 w1 = *(const float4*)(wp + COLS);
                float4 w2 = *(const float4*)(wp + 2 * COLS);
                float4 w3 = *(const float4*)(wp + 3 * COLS);
                a.x = fmaf(xv.x, w0.x, a.x); a.x = fmaf(xv.y, w1.x, a.x);
                a.x = fmaf(xv.z, w2.x, a.x); a.x = fmaf(xv.w, w3.x, a.x);
                a.y = fmaf(xv.x, w0.y, a.y); a.y = fmaf(xv.y, w1.y, a.y);
                a.y = fmaf(xv.z, w2.y, a.y); a.y = fmaf(xv.w, w3.y, a.y);
                a.z = fmaf(xv.x, w0.z, a.z); a.z = fmaf(xv.y, w1.z, a.z);
                a.z = fmaf(xv.z, w2.z, a.z); a.z = fmaf(xv.w, w3.z, a.z);
                a.w = fmaf(xv.x, w0.w, a.w); a.w = fmaf(xv.y, w1.w, a.w);
                a.w = fmaf(xv.z, w2.w, a.w); a.w = fmaf(xv.w, w3.w, a.w);
            }
            const float s = dinv[row];
            a.x *= s; a.y *= s; a.z *= s; a.w *= s;
            float* dst = CM ? &out[cm_base + (size_t)row * 16]
                            : &out[(size_t)row * OUT + gcol];
            *(float4*)dst = a;
        }
    }
}

// XCD-local chunked aggregate with degree-sorted processing order.
// hc chunk-major [NC][n][16]; block slot (blockIdx%8): cc=slot%NC,
// split=slot/NC. Wave's 16 nodes come from order[] (equal degree -> no
// divergence on the gather loop). Output row-major [n][NC*16].
template <int NC, bool RELU>
__global__ __launch_bounds__(256) void agg_chunk_kernel(const float* __restrict__ hc,
                                                        const int* __restrict__ rowptr,
                                                        const int* __restrict__ csr,
                                                        const int* __restrict__ order,
                                                        const float* __restrict__ dinv,
                                                        const float* __restrict__ bias,
                                                        float* __restrict__ out, int n) {
    constexpr int F = NC * 16;
    constexpr int NSPLIT = 8 / NC;
    const int t = threadIdx.x;
    const int slot = blockIdx.x & 7;
    const int cc = slot % NC;                 // chunk
    const int split = slot / NC;              // node-split
    const int g = (blockIdx.x >> 3) * NSPLIT + split;
    const int idx = g * 64 + (t >> 2);
    const int fo = t & 3;                     // float4 index within chunk
    if (idx >= n) return;
    const int node = order[idx];

    const float4* h4 = (const float4*)(hc + (size_t)cc * n * 16);
    float4 self = h4[(size_t)node * 4 + fo];
    float4 a[8];
#pragma unroll
    for (int j = 0; j < 8; ++j) a[j] = make_float4(0.f, 0.f, 0.f, 0.f);

    const int s = rowptr[node];
    const int e = rowptr[node + 1];
    for (int i = s; i < e; i += 8) {
        int   idxv[8];
        float msk[8];
#pragma unroll
        for (int j = 0; j < 8; ++j) {
            const int k = i + j;
            const int kc = (k < e) ? k : (e - 1);
            idxv[j] = csr[kc];
            msk[j] = (k < e) ? 1.f : 0.f;
        }
#pragma unroll
        for (int j = 0; j < 8; ++j) {
            float4 v = h4[(size_t)idxv[j] * 4 + fo];
            a[j].x = fmaf(v.x, msk[j], a[j].x);
            a[j].y = fmaf(v.y, msk[j], a[j].y);
            a[j].z = fmaf(v.z, msk[j], a[j].z);
            a[j].w = fmaf(v.w, msk[j], a[j].w);
        }
    }
    float accx = self.x + ((a[0].x + a[1].x) + (a[2].x + a[3].x)) + ((a[4].x + a[5].x) + (a[6].x + a[7].x));
    float accy = self.y + ((a[0].y + a[1].y) + (a[2].y + a[3].y)) + ((a[4].y + a[5].y) + (a[6].y + a[7].y));
    float accz = self.z + ((a[0].z + a[1].z) + (a[2].z + a[3].z)) + ((a[4].z + a[5].z) + (a[6].z + a[7].z));
    float accw = self.w + ((a[0].w + a[1].w) + (a[2].w + a[3].w)) + ((a[4].w + a[5].w) + (a[6].w + a[7].w));
    const float dc = dinv[node];
    const int f = cc * 16 + fo * 4;
    const float4 b = *(const float4*)&bias[f];
    float ox = fmaf(accx, dc, b.x);
    float oy = fmaf(accy, dc, b.y);
    float oz = fmaf(accz, dc, b.z);
    float ow = fmaf(accw, dc, b.w);
    if (RELU) {
        ox = fmaxf(ox, 0.f); oy = fmaxf(oy, 0.f);
        oz = fmaxf(oz, 0.f); ow = fmaxf(ow, 0.f);
    }
    float4 res = {ox, oy, oz, ow};
    *(float4*)&out[(size_t)node * F + f] = res;
}

extern "C" void kernel_launch(void* const* d_in, const int* in_sizes, int n_in,
                              void* d_out, int out_size, void* d_ws, size_t ws_size,
                              hipStream_t stream) {
    const float* x  = (const float*)d_in[0];
    const int*   ei = (const int*)d_in[1];
    // d_in[2] = batch (unused in eval forward)
    const float* W1 = (const float*)d_in[3];
    const float* b1 = (const float*)d_in[4];
    const float* W2 = (const float*)d_in[5];
    const float* b2 = (const float*)d_in[6];
    const float* W3 = (const float*)d_in[7];
    const float* b3 = (const float*)d_in[8];
    float* out = (float*)d_out;

    const int N = in_sizes[0] / 128;
    const int E = in_sizes[1] / 2;
    const int* erow = ei;       // sources
    const int* ecol = ei + E;   // destinations

    // Workspace layout — round-1-proven footprint (55,200,768 B).
    char* ws = (char*)d_ws;
    auto alloc = [&](size_t bytes) {
        char* p = ws;
        ws += (bytes + 255) & ~(size_t)255;
        return p;
    };
    int*   deg    = (int*)alloc((size_t)N * 4);
    int*   rowptr = (int*)alloc((size_t)(N + 1) * 4);
    int*   cursor = (int*)alloc((size_t)N * 4);
    int*   csr    = (int*)alloc((size_t)E * 4);
    float* dinv   = (float*)alloc((size_t)N * 4);
    float* buf1   = (float*)alloc((size_t)N * 128 * 4);
    float* buf2   = (float*)alloc((size_t)N * 128 * 4);

    // Scan + bucket temporaries alias buf1 (dead until first GEMM writes it).
    int* local = (int*)buf1;
    int* bsums = local + N;
    int* boffs = bsums + 64;
    int* bc    = boffs + 64;   // 64 bucket counts
    int* bcur  = bc + 64;      // 64 bucket cursors
    // order[] aliases cursor (dead after fill_part_kernel).
    int* order = cursor;

    const int nb = (N + 1023) / 1024;  // scan2 assumes nb <= 64

    hipMemsetAsync(deg, 0, (size_t)N * 4, stream);
    count_part_kernel<<<8 * 128, 256, 0, stream>>>(ecol, deg, E, N);
    scan1_kernel<<<nb, 256, 0, stream>>>(deg, local, bsums, N);
    scan2_kernel<<<1, 64, 0, stream>>>(bsums, boffs, rowptr, nb, N);
    scan3_kernel<<<(N + 255) / 256, 256, 0, stream>>>(local, boffs, deg, rowptr, cursor, dinv, N);
    fill_part_kernel<<<8 * 128, 256, 0, stream>>>(erow, ecol, cursor, csr, E, N);

    // Degree-sorted order (cursor is dead now; order aliases it).
    hipMemsetAsync(bc, 0, 64 * 4, stream);
    bucket_count_kernel<<<(N + 255) / 256, 256, 0, stream>>>(deg, bc, N);
    bucket_scan_kernel<<<1, 64, 0, stream>>>(bc, bcur);
    bucket_scatter_kernel<<<(N + 255) / 256, 256, 0, stream>>>(deg, bcur, order, N);

    const int ngroups = (N + 63) / 64;         // 64-node groups
    const int g128 = ((N + 63) / 64) * 2;      // gemm<128,64>: RPI=64, 2 slabs
    const int g32  = (N + 127) / 128;          // gemm<32,32>:  RPI=128, 1 slab
    const int gagg8 = ngroups * 8;             // agg_chunk<8>: NSPLIT=1
    const int gagg2 = ((ngroups + 3) / 4) * 8; // agg_chunk<2>: NSPLIT=4

    // Layer 1: chunk-major GEMM, XCD-local chunked agg
    gemm_kernel<128, 64, true><<<g128, 256, 0, stream>>>(x, W1, dinv, buf1, N);
    agg_chunk_kernel<8, true><<<gagg8, 256, 0, stream>>>(buf1, rowptr, csr, order, dinv, b1, buf2, N);

    // Layer 2
    gemm_kernel<128, 64, true><<<g128, 256, 0, stream>>>(buf2, W2, dinv, buf1, N);
    agg_chunk_kernel<8, true><<<gagg8, 256, 0, stream>>>(buf1, rowptr, csr, order, dinv, b2, buf2, N);

    // Layer 3: logits (no relu), 32 classes -> d_out (chunk-major interm.)
    gemm_kernel<32, 32, true><<<g32, 256, 0, stream>>>(buf2, W3, dinv, buf1, N);
    agg_chunk_kernel<2, false><<<gagg2, 256, 0, stream>>>(buf1, rowptr, csr, order, dinv, b3, out, N);
}

// Round 18
// 288.686 us; speedup vs baseline: 1.8517x; 1.8517x over previous
//
#include <hip/hip_runtime.h>
#include <math.h>

// ---------------------------------------------------------------------------
// 3-layer GCN forward.  (R13/R16 configuration — best verified: 288.8 us)
//   1. deg count — XCD-partitioned by dst range
//   2. two-level exclusive scan -> rowptr + cursor (+ fused dinv)
//      (scan temporaries alias buf1, dead until the first GEMM)
//   3. CSR fill — XCD-partitioned by dst range
//   4. all layers: GEMM (W slab in 32KB LDS, R=4 reg blocking) writing
//      CHUNK-MAJOR [OUT/16][N][16]; then XCD-local chunked aggregate:
//      block owns chunk (blockIdx%8)%NC -> its XCD's L2-resident 3.2MB
//      slice; 4 lanes x float4 per node, 8-deep predicated unroll.
//      agg writes row-major for the next GEMM / output.
// ---------------------------------------------------------------------------

__global__ __launch_bounds__(256) void count_part_kernel(const int* __restrict__ col,
                                                         int* __restrict__ deg, int E, int n) {
    const int part = blockIdx.x & 7;
    const int nb = gridDim.x >> 3;
    const int chunk = blockIdx.x >> 3;
    const int lo = (int)(((long long)part * n) >> 3);
    const int hi = (int)(((long long)(part + 1) * n) >> 3);
    for (int e = chunk * 256 + threadIdx.x; e < E; e += nb * 256) {
        const int c = col[e];
        if (c >= lo && c < hi) atomicAdd(&deg[c], 1);
    }
}

__global__ __launch_bounds__(256) void scan1_kernel(const int* __restrict__ deg,
                                                    int* __restrict__ local,
                                                    int* __restrict__ blocksums, int n) {
    __shared__ int wsum[4];
    const int t = threadIdx.x;
    const int lane = t & 63;
    const int wv = t >> 6;
    const int base = blockIdx.x * 1024 + t * 4;
    int a0 = (base + 0 < n) ? deg[base + 0] : 0;
    int a1 = (base + 1 < n) ? deg[base + 1] : 0;
    int a2 = (base + 2 < n) ? deg[base + 2] : 0;
    int a3 = (base + 3 < n) ? deg[base + 3] : 0;
    const int tot = a0 + a1 + a2 + a3;
    int incl = tot;
#pragma unroll
    for (int off = 1; off < 64; off <<= 1) {
        int u = __shfl_up(incl, off);
        if (lane >= off) incl += u;
    }
    if (lane == 63) wsum[wv] = incl;
    __syncthreads();
    int woff = 0;
#pragma unroll
    for (int w = 0; w < 4; ++w) woff += (w < wv) ? wsum[w] : 0;
    const int excl = woff + incl - tot;
    if (base + 0 < n) local[base + 0] = excl;
    if (base + 1 < n) local[base + 1] = excl + a0;
    if (base + 2 < n) local[base + 2] = excl + a0 + a1;
    if (base + 3 < n) local[base + 3] = excl + a0 + a1 + a2;
    if (t == 255) blocksums[blockIdx.x] = woff + incl;
}

__global__ void scan2_kernel(const int* __restrict__ blocksums, int* __restrict__ blockoff,
                             int* __restrict__ rowptr, int nb, int n) {
    const int lane = threadIdx.x;  // 64 threads
    int v = (lane < nb) ? blocksums[lane] : 0;
    int incl = v;
#pragma unroll
    for (int off = 1; off < 64; off <<= 1) {
        int u = __shfl_up(incl, off);
        if (lane >= off) incl += u;
    }
    if (lane < nb) blockoff[lane] = incl - v;
    if (lane == 63) rowptr[n] = incl;
}

__global__ void scan3_kernel(const int* __restrict__ local, const int* __restrict__ blockoff,
                             const int* __restrict__ deg, int* __restrict__ rowptr,
                             int* __restrict__ cursor, float* __restrict__ dinv, int n) {
    int i = blockIdx.x * blockDim.x + threadIdx.x;
    if (i < n) {
        const int v = local[i] + blockoff[i >> 10];
        rowptr[i] = v;
        cursor[i] = v;
        dinv[i] = rsqrtf((float)deg[i] + 1.0f);
    }
}

__global__ __launch_bounds__(256) void fill_part_kernel(const int* __restrict__ row,
                                                        const int* __restrict__ col,
                                                        int* __restrict__ cursor,
                                                        int* __restrict__ csr, int E, int n) {
    const int part = blockIdx.x & 7;
    const int nb = gridDim.x >> 3;
    const int chunk = blockIdx.x >> 3;
    const int lo = (int)(((long long)part * n) >> 3);
    const int hi = (int)(((long long)(part + 1) * n) >> 3);
    for (int e = chunk * 256 + threadIdx.x; e < E; e += nb * 256) {
        const int c = col[e];
        if (c >= lo && c < hi) {
            const int r = row[e];
            if ((unsigned)r < (unsigned)n) {
                const int pos = atomicAdd(&cursor[c], 1);
                csr[pos] = r;
            }
        }
    }
}

// h[:, c0:c0+COLS] = X @ W[:, c0:c0+COLS], row r scaled by dinv[r].
// W column-slab staged in LDS (COLS=64 -> 32KB -> 5 blocks/CU). R=4 rows
// register-blocked per thread: 16 LDS floats feed 64 FMAs.
// CM: output chunk-major [OUT/16][n][16]; else row-major [n][OUT].
template <int OUT, int COLS, bool CM>
__global__ __launch_bounds__(256) void gemm_kernel(const float* __restrict__ X,
                                                   const float* __restrict__ W,
                                                   const float* __restrict__ dinv,
                                                   float* __restrict__ out, int n) {
    constexpr int NSLAB = OUT / COLS;
    constexpr int CQ  = COLS / 4;
    constexpr int RG  = 256 / CQ;
    constexpr int R   = 4;
    constexpr int RPI = RG * R;
    __shared__ float Wl[128 * COLS];

    const int t = threadIdx.x;
    const int c0 = (int)(blockIdx.x % NSLAB) * COLS;
    const int rowblk = blockIdx.x / NSLAB;

    for (int i = t; i < 128 * CQ; i += 256) {
        const int k  = i / CQ;
        const int cc = i % CQ;
        ((float4*)Wl)[i] = *(const float4*)&W[(size_t)k * OUT + c0 + cc * 4];
    }
    __syncthreads();

    const int cq = t % CQ;
    const int rg = t / CQ;
    const float4* X4 = (const float4*)X;
    const int gcol = c0 + cq * 4;                 // global output column
    const size_t cm_base = (size_t)(gcol >> 4) * n * 16 + (gcol & 15);

    const int r0 = rowblk * RPI + rg * R;
    float4 acc[R];
#pragma unroll
    for (int r = 0; r < R; ++r) acc[r] = make_float4(0.f, 0.f, 0.f, 0.f);

    if (r0 + R <= n) {
#pragma unroll 4
        for (int k4 = 0; k4 < 32; ++k4) {
            const float* wp = &Wl[k4 * 4 * COLS + cq * 4];
            float4 w0 = *(const float4*)(wp);
            float4 w1 = *(const float4*)(wp + COLS);
            float4 w2 = *(const float4*)(wp + 2 * COLS);
            float4 w3 = *(const float4*)(wp + 3 * COLS);
#pragma unroll
            for (int r = 0; r < R; ++r) {
                float4 xv = X4[(size_t)(r0 + r) * 32 + k4];
                acc[r].x = fmaf(xv.x, w0.x, acc[r].x);
                acc[r].x = fmaf(xv.y, w1.x, acc[r].x);
                acc[r].x = fmaf(xv.z, w2.x, acc[r].x);
                acc[r].x = fmaf(xv.w, w3.x, acc[r].x);
                acc[r].y = fmaf(xv.x, w0.y, acc[r].y);
                acc[r].y = fmaf(xv.y, w1.y, acc[r].y);
                acc[r].y = fmaf(xv.z, w2.y, acc[r].y);
                acc[r].y = fmaf(xv.w, w3.y, acc[r].y);
                acc[r].z = fmaf(xv.x, w0.z, acc[r].z);
                acc[r].z = fmaf(xv.y, w1.z, acc[r].z);
                acc[r].z = fmaf(xv.z, w2.z, acc[r].z);
                acc[r].z = fmaf(xv.w, w3.z, acc[r].z);
                acc[r].w = fmaf(xv.x, w0.w, acc[r].w);
                acc[r].w = fmaf(xv.y, w1.w, acc[r].w);
                acc[r].w = fmaf(xv.z, w2.w, acc[r].w);
                acc[r].w = fmaf(xv.w, w3.w, acc[r].w);
            }
        }
#pragma unroll
        for (int r = 0; r < R; ++r) {
            const float s = dinv[r0 + r];
            acc[r].x *= s; acc[r].y *= s; acc[r].z *= s; acc[r].w *= s;
            float* dst = CM ? &out[cm_base + (size_t)(r0 + r) * 16]
                            : &out[(size_t)(r0 + r) * OUT + gcol];
            *(float4*)dst = acc[r];
        }
    } else if (r0 < n) {
        for (int r = 0; r < R; ++r) {
            const int row = r0 + r;
            if (row >= n) break;
            float4 a = make_float4(0.f, 0.f, 0.f, 0.f);
            for (int k4 = 0; k4 < 32; ++k4) {
                float4 xv = X4[(size_t)row * 32 + k4];
                const float* wp = &Wl[k4 * 4 * COLS + cq * 4];
                float4 w0 = *(const float4*)(wp);
                float4 w1 = *(const float4*)(wp + COLS);
                float4 w2 = *(const float4*)(wp + 2 * COLS);
                float4 w3 = *(const float4*)(wp + 3 * COLS);
                a.x = fmaf(xv.x, w0.x, a.x); a.x = fmaf(xv.y, w1.x, a.x);
                a.x = fmaf(xv.z, w2.x, a.x); a.x = fmaf(xv.w, w3.x, a.x);
                a.y = fmaf(xv.x, w0.y, a.y); a.y = fmaf(xv.y, w1.y, a.y);
                a.y = fmaf(xv.z, w2.y, a.y); a.y = fmaf(xv.w, w3.y, a.y);
                a.z = fmaf(xv.x, w0.z, a.z); a.z = fmaf(xv.y, w1.z, a.z);
                a.z = fmaf(xv.z, w2.z, a.z); a.z = fmaf(xv.w, w3.z, a.z);
                a.w = fmaf(xv.x, w0.w, a.w); a.w = fmaf(xv.y, w1.w, a.w);
                a.w = fmaf(xv.z, w2.w, a.w); a.w = fmaf(xv.w, w3.w, a.w);
            }
            const float s = dinv[row];
            a.x *= s; a.y *= s; a.z *= s; a.w *= s;
            float* dst = CM ? &out[cm_base + (size_t)row * 16]
                            : &out[(size_t)row * OUT + gcol];
            *(float4*)dst = a;
        }
    }
}

// XCD-local chunked aggregate. hc chunk-major [NC][n][16]; block slot
// (blockIdx%8): cc = slot%NC, node-split = slot/NC. 4 lanes x float4 per
// node, 64 nodes/block, 8-deep predicated unroll. Output row-major [n][NC*16].
template <int NC, bool RELU>
__global__ __launch_bounds__(256) void agg_chunk_kernel(const float* __restrict__ hc,
                                                        const int* __restrict__ rowptr,
                                                        const int* __restrict__ csr,
                                                        const float* __restrict__ dinv,
                                                        const float* __restrict__ bias,
                                                        float* __restrict__ out, int n) {
    constexpr int F = NC * 16;
    constexpr int NSPLIT = 8 / NC;
    const int t = threadIdx.x;
    const int slot = blockIdx.x & 7;
    const int cc = slot % NC;                 // chunk
    const int split = slot / NC;              // node-split
    const int g = (blockIdx.x >> 3) * NSPLIT + split;
    const int node = g * 64 + (t >> 2);
    const int fo = t & 3;                     // float4 index within chunk
    if (node >= n) return;

    const float4* h4 = (const float4*)(hc + (size_t)cc * n * 16);
    float4 self = h4[(size_t)node * 4 + fo];
    float4 a[8];
#pragma unroll
    for (int j = 0; j < 8; ++j) a[j] = make_float4(0.f, 0.f, 0.f, 0.f);

    const int s = rowptr[node];
    const int e = rowptr[node + 1];
    for (int i = s; i < e; i += 8) {
        int   idx[8];
        float msk[8];
#pragma unroll
        for (int j = 0; j < 8; ++j) {
            const int k = i + j;
            const int kc = (k < e) ? k : (e - 1);
            idx[j] = csr[kc];
            msk[j] = (k < e) ? 1.f : 0.f;
        }
#pragma unroll
        for (int j = 0; j < 8; ++j) {
            float4 v = h4[(size_t)idx[j] * 4 + fo];
            a[j].x = fmaf(v.x, msk[j], a[j].x);
            a[j].y = fmaf(v.y, msk[j], a[j].y);
            a[j].z = fmaf(v.z, msk[j], a[j].z);
            a[j].w = fmaf(v.w, msk[j], a[j].w);
        }
    }
    float accx = self.x + ((a[0].x + a[1].x) + (a[2].x + a[3].x)) + ((a[4].x + a[5].x) + (a[6].x + a[7].x));
    float accy = self.y + ((a[0].y + a[1].y) + (a[2].y + a[3].y)) + ((a[4].y + a[5].y) + (a[6].y + a[7].y));
    float accz = self.z + ((a[0].z + a[1].z) + (a[2].z + a[3].z)) + ((a[4].z + a[5].z) + (a[6].z + a[7].z));
    float accw = self.w + ((a[0].w + a[1].w) + (a[2].w + a[3].w)) + ((a[4].w + a[5].w) + (a[6].w + a[7].w));
    const float dc = dinv[node];
    const int f = cc * 16 + fo * 4;
    const float4 b = *(const float4*)&bias[f];
    float ox = fmaf(accx, dc, b.x);
    float oy = fmaf(accy, dc, b.y);
    float oz = fmaf(accz, dc, b.z);
    float ow = fmaf(accw, dc, b.w);
    if (RELU) {
        ox = fmaxf(ox, 0.f); oy = fmaxf(oy, 0.f);
        oz = fmaxf(oz, 0.f); ow = fmaxf(ow, 0.f);
    }
    float4 res = {ox, oy, oz, ow};
    *(float4*)&out[(size_t)node * F + f] = res;
}

extern "C" void kernel_launch(void* const* d_in, const int* in_sizes, int n_in,
                              void* d_out, int out_size, void* d_ws, size_t ws_size,
                              hipStream_t stream) {
    const float* x  = (const float*)d_in[0];
    const int*   ei = (const int*)d_in[1];
    // d_in[2] = batch (unused in eval forward)
    const float* W1 = (const float*)d_in[3];
    const float* b1 = (const float*)d_in[4];
    const float* W2 = (const float*)d_in[5];
    const float* b2 = (const float*)d_in[6];
    const float* W3 = (const float*)d_in[7];
    const float* b3 = (const float*)d_in[8];
    float* out = (float*)d_out;

    const int N = in_sizes[0] / 128;
    const int E = in_sizes[1] / 2;
    const int* erow = ei;       // sources
    const int* ecol = ei + E;   // destinations

    // Workspace layout — round-1-proven footprint (55,200,768 B).
    char* ws = (char*)d_ws;
    auto alloc = [&](size_t bytes) {
        char* p = ws;
        ws += (bytes + 255) & ~(size_t)255;
        return p;
    };
    int*   deg    = (int*)alloc((size_t)N * 4);
    int*   rowptr = (int*)alloc((size_t)(N + 1) * 4);
    int*   cursor = (int*)alloc((size_t)N * 4);
    int*   csr    = (int*)alloc((size_t)E * 4);
    float* dinv   = (float*)alloc((size_t)N * 4);
    float* buf1   = (float*)alloc((size_t)N * 128 * 4);
    float* buf2   = (float*)alloc((size_t)N * 128 * 4);

    // Scan temporaries alias buf1 (dead until first GEMM writes it).
    int* local = (int*)buf1;
    int* bsums = local + N;
    int* boffs = bsums + 64;

    const int nb = (N + 1023) / 1024;  // scan2 assumes nb <= 64

    hipMemsetAsync(deg, 0, (size_t)N * 4, stream);
    count_part_kernel<<<8 * 128, 256, 0, stream>>>(ecol, deg, E, N);
    scan1_kernel<<<nb, 256, 0, stream>>>(deg, local, bsums, N);
    scan2_kernel<<<1, 64, 0, stream>>>(bsums, boffs, rowptr, nb, N);
    scan3_kernel<<<(N + 255) / 256, 256, 0, stream>>>(local, boffs, deg, rowptr, cursor, dinv, N);
    fill_part_kernel<<<8 * 128, 256, 0, stream>>>(erow, ecol, cursor, csr, E, N);

    const int ngroups = (N + 63) / 64;         // 64-node groups
    const int g128 = ((N + 63) / 64) * 2;      // gemm<128,64>: RPI=64, 2 slabs
    const int g32  = (N + 127) / 128;          // gemm<32,32>:  RPI=128, 1 slab
    const int gagg8 = ngroups * 8;             // agg_chunk<8>: NSPLIT=1
    const int gagg2 = ((ngroups + 3) / 4) * 8; // agg_chunk<2>: NSPLIT=4

    // Layer 1: chunk-major GEMM, XCD-local chunked agg
    gemm_kernel<128, 64, true><<<g128, 256, 0, stream>>>(x, W1, dinv, buf1, N);
    agg_chunk_kernel<8, true><<<gagg8, 256, 0, stream>>>(buf1, rowptr, csr, dinv, b1, buf2, N);

    // Layer 2
    gemm_kernel<128, 64, true><<<g128, 256, 0, stream>>>(buf2, W2, dinv, buf1, N);
    agg_chunk_kernel<8, true><<<gagg8, 256, 0, stream>>>(buf1, rowptr, csr, dinv, b2, buf2, N);

    // Layer 3: logits (no relu), 32 classes -> d_out (chunk-major interm.)
    gemm_kernel<32, 32, true><<<g32, 256, 0, stream>>>(buf2, W3, dinv, buf1, N);
    agg_chunk_kernel<2, false><<<gagg2, 256, 0, stream>>>(buf1, rowptr, csr, dinv, b3, out, N);
}